// Round 5
// baseline (112.897 us; speedup 1.0000x reference)
//
#include <hip/hip_runtime.h>
#include <stdint.h>
#include <stddef.h>

// MambaMesh random-walk + gather-recenter.  R5: split hash-gen / walk.
// PRNG (bit-exact vs JAX partitionable Threefry, verified R1-R4, absmax 0.0):
//   split(key,n)[j]        = threefry2x32(key; 0, j)   (both output words)
//   random_bits(key,32,()) = xor-fold of threefry2x32(key; 0, 0)
// R4 lesson: 1-level triplet prefetch cannot beat the pointer-chase floor
// (next row IS one of the in-flight loads -> per-iter ~ load latency), and
// prewarm changed nothing (FETCH_SIZE flat). ~30 us of the 50 us kernel is
// unattributed stall. R5 splits into two dispatches for speed + attribution:
//   k1: chains (wave0, lane-parallel) + trees (all waves) -> keys+codes to ws
//   k2: barrier-free walk, 4 waves/block; per-step code/key via __shfl from
//       per-lane registers (no LDS, no global PRNG traffic in the loop).
// Fallback: fused R4-style kernel if ws_size < 3 MB.

namespace {

__device__ __forceinline__ uint32_t rotl32(uint32_t x, int r) {
  return (x << r) | (x >> (32 - r));
}

// Threefry-2x32, 20 rounds — exactly JAX's threefry2x32_p.
__device__ __forceinline__ void tf2x32(uint32_t ka, uint32_t kb,
                                       uint32_t x0, uint32_t x1,
                                       uint32_t& o0, uint32_t& o1) {
  const uint32_t kc = ka ^ kb ^ 0x1BD11BDAu;
  x0 += ka; x1 += kb;
#define TF_R4(r0, r1, r2, r3)                          \
  x0 += x1; x1 = rotl32(x1, r0); x1 ^= x0;             \
  x0 += x1; x1 = rotl32(x1, r1); x1 ^= x0;             \
  x0 += x1; x1 = rotl32(x1, r2); x1 ^= x0;             \
  x0 += x1; x1 = rotl32(x1, r3); x1 ^= x0;
  TF_R4(13, 15, 26, 6)  x0 += kb; x1 += kc + 1u;
  TF_R4(17, 29, 16, 24) x0 += kc; x1 += ka + 2u;
  TF_R4(13, 15, 26, 6)  x0 += ka; x1 += kb + 3u;
  TF_R4(17, 29, 16, 24) x0 += kb; x1 += kc + 4u;
  TF_R4(13, 15, 26, 6)  x0 += kc; x1 += ka + 5u;
#undef TF_R4
  o0 = x0; o1 = x1;
}

// (hi, lo) bits of jax.random.randint(key, (), 0, span): span-independent.
__device__ __forceinline__ void randbits(uint32_t ka, uint32_t kb,
                                         uint32_t& hi, uint32_t& lo) {
  uint32_t s0a, s0b, s1a, s1b, h0, h1;
  tf2x32(ka, kb, 0u, 0u, s0a, s0b);   // split(key)[0]
  tf2x32(ka, kb, 0u, 1u, s1a, s1b);   // split(key)[1]
  tf2x32(s0a, s0b, 0u, 0u, h0, h1);
  hi = h0 ^ h1;
  tf2x32(s1a, s1b, 0u, 0u, h0, h1);
  lo = h0 ^ h1;
}

__device__ __forceinline__ uint32_t r_generic(uint32_t hi, uint32_t lo,
                                              uint32_t span) {
  uint32_t mult = 65536u % span;
  mult = (mult * mult) % span;
  return ((hi % span) * mult + (lo % span)) % span;
}

// pick code: r3 (span=3 result) in bits 0..1, r2 (span=2 result) in bit 2.
__device__ __forceinline__ uint32_t pick_code(uint32_t hi, uint32_t lo) {
  return ((hi % 3u + lo % 3u) % 3u) | ((lo & 1u) << 2);
}

constexpr int CH = 64;       // cached chain length (covers seq_len 63)
constexpr int K1_WPB = 16;   // k1: walks per block (1024 thr)
constexpr int K2_WPB = 4;    // k2: walks per block (256 thr, barrier-free)

// ---------------- Kernel 1: keys + pick codes -> workspace ----------------
__global__ __launch_bounds__(1024) void keys_kernel(
    uint2* __restrict__ keys_g, uint32_t* __restrict__ codes_g,
    int num_walks) {
  __shared__ uint2 keys[K1_WPB][CH + 1];

  const int tid = threadIdx.x;
  const int wv = tid >> 6, lane = tid & 63;
  const int w0 = blockIdx.x * K1_WPB;
  const int w = w0 + wv;

  // A0: wave 0, lanes 0..15 compute the block's 16 carry chains.
  if (wv == 0 && lane < K1_WPB && (w0 + lane) < num_walks) {
    uint32_t ka, kb;
    tf2x32(0u, 42u, 0u, (uint32_t)(w0 + lane), ka, kb);  // k_0
    keys[lane][0] = make_uint2(ka, kb);
#pragma clang loop unroll(disable)
    for (int c = 1; c < CH; ++c) {
      tf2x32(ka, kb, 0u, 0u, ka, kb);
      keys[lane][c] = make_uint2(ka, kb);
    }
  }
  __syncthreads();
  if (w >= num_walks) return;

  // A1: lane c computes step-c randint tree; store key + code coalesced.
  const uint2 kc = keys[wv][lane];
  uint32_t k1a, k1b, hi, lo;
  tf2x32(kc.x, kc.y, 0u, 1u, k1a, k1b);  // k1 = split(k,4)[1]
  randbits(k1a, k1b, hi, lo);
  keys_g[(size_t)w * CH + lane]  = kc;
  codes_g[(size_t)w * CH + lane] = pick_code(hi, lo);
}

// ---------------- Kernel 2: the walk (barrier-free) -----------------------
__global__ __launch_bounds__(256) void walk_kernel(
    const float* __restrict__ xyz, const int* __restrict__ nbrs,
    const int* __restrict__ centers, const int* __restrict__ n_faces_p,
    const int* __restrict__ seq_len_p, float* __restrict__ out,
    const uint2* __restrict__ keys_g, const uint32_t* __restrict__ codes_g,
    int s0, int num_walks, int Lp1) {
  const int tid = threadIdx.x;
  const int wv = tid >> 6, lane = tid & 63;
  const int w = blockIdx.x * K2_WPB + wv;
  if (w >= num_walks) return;

  const int N = *n_faces_p;    // 20000
  const int L = *seq_len_p;    // 63
  const int B = s0 / (3 * N);
  const int G = num_walks / B;
  const int b = w / G;
  const int* __restrict__ nb   = nbrs + (size_t)b * N * 3;
  const float* __restrict__ xb = xyz + (size_t)b * N * 3;

  // Per-lane PRNG state for this wave's walk: lane t = step t.
  const uint2 mykey = keys_g[(size_t)w * CH + lane];
  const uint32_t mycode = codes_g[(size_t)w * CH + lane];

  const int f0 = centers[w];
  int3 row = *reinterpret_cast<const int3*>(nb + 3 * (size_t)f0);
  // First speculative triplet (depends on row).
  int3 t0 = *reinterpret_cast<const int3*>(nb + 3 * (size_t)row.x);
  int3 t1 = *reinterpret_cast<const int3*>(nb + 3 * (size_t)row.y);
  int3 t2 = *reinterpret_cast<const int3*>(nb + 3 * (size_t)row.z);

  // visited set: lane j holds the j-th visited node (slot 0 = f0).
  int hist  = (lane == 0) ? f0 : -1;
  int hist2 = -1;              // slots 64..127 (backtrack overflow; ~never)
  int seqr  = (lane == 0) ? f0 : -1;  // lane t = seq[t]

  uint32_t extka = 0, extkb = 0;
  int extc = -1;  // lazy chain extension beyond CH (only after backtracks)

  auto get_key = [&](int idx, uint32_t& ra, uint32_t& rb) {
    if (idx < CH) {
      ra = (uint32_t)__shfl((int)mykey.x, idx);
      rb = (uint32_t)__shfl((int)mykey.y, idx);
    } else {
      if (extc < 0) {
        extka = (uint32_t)__shfl((int)mykey.x, CH - 1);
        extkb = (uint32_t)__shfl((int)mykey.y, CH - 1);
        extc = CH - 1;
      }
      while (extc < idx) { tf2x32(extka, extkb, 0u, 0u, extka, extkb); ++extc; }
      ra = extka; rb = extkb;
    }
  };

  uint32_t code_next = (uint32_t)__shfl((int)mycode, 0);
  int i = 1, bs = 1, c = 0;

  while (i <= L) {
    const int idx = c; ++c;
    const bool deep = (idx >= CH);  // hist2 in use
    const uint32_t codeP = code_next;
    code_next = (uint32_t)__shfl((int)mycode, (c < CH) ? c : 0);  // prefetch

    const int n0 = row.x, n1 = row.y, n2 = row.z;
    int v0 = __any(hist == n0), v1 = __any(hist == n1), v2 = __any(hist == n2);
    if (deep) {
      v0 |= __any(hist2 == n0); v1 |= __any(hist2 == n1); v2 |= __any(hist2 == n2);
    }
    const int u0 = 1 - v0, u1 = 1 - v1, u2 = 1 - v2;
    const int cnt = u0 + u1 + u2;

    int to_add;
    int sel = -1;        // >=0: common path, row select from triplet
    bool hit = false;
    int bsf = bs;
    if (cnt > 0) {
      uint32_t code;
      if (!deep) {
        code = codeP;
      } else {  // rare: live tree beyond cached steps
        uint32_t ia, ib, k1a, k1b, hi, lo;
        get_key(idx, ia, ib);
        tf2x32(ia, ib, 0u, 1u, k1a, k1b);
        randbits(k1a, k1b, hi, lo);
        code = pick_code(hi, lo);
      }
      const int r3 = (int)(code & 3u), r2 = (int)((code >> 2) & 1u);
      const int target = (cnt == 3 ? r3 : (cnt == 2 ? r2 : 0)) + 1;
      sel = (u0 == target) ? 0 : ((u0 + u1 == target) ? 1 : 2);
      to_add = (sel == 0) ? n0 : ((sel == 1) ? n1 : n2);
    } else {
      // ---- rare backtrack path (live hashing, bit-exact) ----
      uint32_t kia, kib;
      get_key(idx, kia, kib);
      uint32_t kka, kkb;
      tf2x32(kia, kib, 0u, 2u, kka, kkb);  // k2
      bool found = false;
      int ta = 0, bsc = bs;
      while (!found && i > bsc) {
        uint32_t ca, cb, kpa, kpb;
        tf2x32(kka, kkb, 0u, 0u, ca, cb);    // kk = split[0]
        tf2x32(kka, kkb, 0u, 1u, kpa, kpb);  // kp = split[1]
        const int back = __shfl(seqr, i - bsc - 1);
        const int3 br = *reinterpret_cast<const int3*>(nb + 3 * (size_t)back);
        int w0m = __any(hist == br.x), w1m = __any(hist == br.y), w2m = __any(hist == br.z);
        if (deep) {
          w0m |= __any(hist2 == br.x); w1m |= __any(hist2 == br.y); w2m |= __any(hist2 == br.z);
        }
        const int e0 = 1 - w0m, e1 = 1 - w1m, e2 = 1 - w2m;
        const int bc = e0 + e1 + e2;
        if (bc > 0) {
          uint32_t bhi, blo;
          randbits(kpa, kpb, bhi, blo);
          const uint32_t bcode = pick_code(bhi, blo);
          const int r3 = (int)(bcode & 3u), r2 = (int)((bcode >> 2) & 1u);
          const int t2v = (bc == 3 ? r3 : (bc == 2 ? r2 : 0)) + 1;
          ta = (e0 == t2v) ? br.x : ((e0 + e1 == t2v) ? br.y : br.z);
          found = true;
        } else {
          bsc += 2;
        }
        kka = ca; kkb = cb;
      }
      if (found) {
        to_add = ta; hit = true; bsf = bsc;
      } else {
        uint32_t k3a, k3b, rhi, rlo;
        tf2x32(kia, kib, 0u, 3u, k3a, k3b);  // k3
        randbits(k3a, k3b, rhi, rlo);
        to_add = (int)r_generic(rhi, rlo, (uint32_t)N);
      }
    }

    int i_new, up;
    if (hit) { i_new = i - bsf; bs = bsf; up = i - 1; }   // splat [i_new, i)
    else     { i_new = i;       bs = 1;   up = i; }
    seqr = (lane >= i_new && lane <= up) ? to_add : seqr;

    const int slot = idx + 1;
    if (slot < CH)            hist  = (lane == slot)      ? to_add : hist;
    else if (slot < 2 * CH)   hist2 = (lane == slot - CH) ? to_add : hist2;
    // slot >= 128: needs ~32 backtracks in one walk — P < 1e-100 here.

    i = i_new + 1;

    // Next row: common path = select from in-flight triplet; rare = reload.
    if (sel >= 0) {
      row.x = (sel == 0) ? t0.x : ((sel == 1) ? t1.x : t2.x);
      row.y = (sel == 0) ? t0.y : ((sel == 1) ? t1.y : t2.y);
      row.z = (sel == 0) ? t0.z : ((sel == 1) ? t1.z : t2.z);
    } else {
      row = *reinterpret_cast<const int3*>(nb + 3 * (size_t)to_add);
    }
    // Issue next speculative triplet.
    t0 = *reinterpret_cast<const int3*>(nb + 3 * (size_t)row.x);
    t1 = *reinterpret_cast<const int3*>(nb + 3 * (size_t)row.y);
    t2 = *reinterpret_cast<const int3*>(nb + 3 * (size_t)row.z);
  }

  // ---- Epilogue: lane t holds seq[t] ------------------------------------
  const float cx = xb[3 * (size_t)f0 + 0];
  const float cy = xb[3 * (size_t)f0 + 1];
  const float cz = xb[3 * (size_t)f0 + 2];
  if (lane < Lp1) {
    const int node = seqr;
    float3 v;
    v.x = xb[3 * (size_t)node + 0] - cx;
    v.y = xb[3 * (size_t)node + 1] - cy;
    v.z = xb[3 * (size_t)node + 2] - cz;
    *reinterpret_cast<float3*>(out + ((size_t)w * Lp1 + lane) * 3) = v;
  }
}

// ---------------- Fallback: fused single kernel (R4 structure) ------------
__global__ __launch_bounds__(1024) void fused_kernel(
    const float* __restrict__ xyz, const int* __restrict__ nbrs,
    const int* __restrict__ centers, const int* __restrict__ n_faces_p,
    const int* __restrict__ seq_len_p, float* __restrict__ out,
    int s0, int num_walks, int Lp1) {
  __shared__ uint2 keys[K1_WPB][CH + 1];
  __shared__ uint32_t pre[K1_WPB][CH];

  const int tid = threadIdx.x;
  const int wv = tid >> 6, lane = tid & 63;
  const int w0 = blockIdx.x * K1_WPB;
  const int w = w0 + wv;
  const bool active = (w < num_walks);

  const int N = *n_faces_p;
  const int L = *seq_len_p;
  const int B = s0 / (3 * N);
  const int G = num_walks / B;
  const int b = (active ? w : w0) / G;
  const int* __restrict__ nb   = nbrs + (size_t)b * N * 3;
  const float* __restrict__ xb = xyz + (size_t)b * N * 3;

  int f0 = 0;
  int3 row = make_int3(0, 0, 0);
  if (active) {
    f0 = centers[w];
    row = *reinterpret_cast<const int3*>(nb + 3 * (size_t)f0);
  }

  if (wv == 0 && lane < K1_WPB && (w0 + lane) < num_walks) {
    uint32_t ka, kb;
    tf2x32(0u, 42u, 0u, (uint32_t)(w0 + lane), ka, kb);
    keys[lane][0] = make_uint2(ka, kb);
#pragma clang loop unroll(disable)
    for (int c = 1; c < CH; ++c) {
      tf2x32(ka, kb, 0u, 0u, ka, kb);
      keys[lane][c] = make_uint2(ka, kb);
    }
  }
  __syncthreads();
  if (!active) return;

  int3 t0 = *reinterpret_cast<const int3*>(nb + 3 * (size_t)row.x);
  int3 t1 = *reinterpret_cast<const int3*>(nb + 3 * (size_t)row.y);
  int3 t2 = *reinterpret_cast<const int3*>(nb + 3 * (size_t)row.z);

  {
    const uint2 kc = keys[wv][lane];
    uint32_t k1a, k1b, hi, lo;
    tf2x32(kc.x, kc.y, 0u, 1u, k1a, k1b);
    randbits(k1a, k1b, hi, lo);
    pre[wv][lane] = pick_code(hi, lo);
  }

  int hist  = (lane == 0) ? f0 : -1;
  int hist2 = -1;
  int seqr  = (lane == 0) ? f0 : -1;

  uint32_t extka = 0, extkb = 0;
  int extc = -1;

  auto get_key = [&](int idx, uint32_t& ra, uint32_t& rb) {
    if (idx < CH) {
      const uint2 q = keys[wv][idx]; ra = q.x; rb = q.y;
    } else {
      if (extc < 0) { const uint2 q = keys[wv][CH - 1]; extka = q.x; extkb = q.y; extc = CH - 1; }
      while (extc < idx) { tf2x32(extka, extkb, 0u, 0u, extka, extkb); ++extc; }
      ra = extka; rb = extkb;
    }
  };

  uint32_t code_next = pre[wv][0];
  int i = 1, bs = 1, c = 0;

  while (i <= L) {
    const int idx = c; ++c;
    const bool deep = (idx >= CH);
    const uint32_t codeP = code_next;
    code_next = pre[wv][(c < CH) ? c : 0];

    const int n0 = row.x, n1 = row.y, n2 = row.z;
    int v0 = __any(hist == n0), v1 = __any(hist == n1), v2 = __any(hist == n2);
    if (deep) {
      v0 |= __any(hist2 == n0); v1 |= __any(hist2 == n1); v2 |= __any(hist2 == n2);
    }
    const int u0 = 1 - v0, u1 = 1 - v1, u2 = 1 - v2;
    const int cnt = u0 + u1 + u2;

    int to_add;
    int sel = -1;
    bool hit = false;
    int bsf = bs;
    if (cnt > 0) {
      uint32_t code;
      if (!deep) {
        code = codeP;
      } else {
        uint32_t ia, ib, k1a, k1b, hi, lo;
        get_key(idx, ia, ib);
        tf2x32(ia, ib, 0u, 1u, k1a, k1b);
        randbits(k1a, k1b, hi, lo);
        code = pick_code(hi, lo);
      }
      const int r3 = (int)(code & 3u), r2 = (int)((code >> 2) & 1u);
      const int target = (cnt == 3 ? r3 : (cnt == 2 ? r2 : 0)) + 1;
      sel = (u0 == target) ? 0 : ((u0 + u1 == target) ? 1 : 2);
      to_add = (sel == 0) ? n0 : ((sel == 1) ? n1 : n2);
    } else {
      uint32_t kia, kib;
      get_key(idx, kia, kib);
      uint32_t kka, kkb;
      tf2x32(kia, kib, 0u, 2u, kka, kkb);
      bool found = false;
      int ta = 0, bsc = bs;
      while (!found && i > bsc) {
        uint32_t ca, cb, kpa, kpb;
        tf2x32(kka, kkb, 0u, 0u, ca, cb);
        tf2x32(kka, kkb, 0u, 1u, kpa, kpb);
        const int back = __shfl(seqr, i - bsc - 1);
        const int3 br = *reinterpret_cast<const int3*>(nb + 3 * (size_t)back);
        int w0m = __any(hist == br.x), w1m = __any(hist == br.y), w2m = __any(hist == br.z);
        if (deep) {
          w0m |= __any(hist2 == br.x); w1m |= __any(hist2 == br.y); w2m |= __any(hist2 == br.z);
        }
        const int e0 = 1 - w0m, e1 = 1 - w1m, e2 = 1 - w2m;
        const int bc = e0 + e1 + e2;
        if (bc > 0) {
          uint32_t bhi, blo;
          randbits(kpa, kpb, bhi, blo);
          const uint32_t bcode = pick_code(bhi, blo);
          const int r3 = (int)(bcode & 3u), r2 = (int)((bcode >> 2) & 1u);
          const int t2v = (bc == 3 ? r3 : (bc == 2 ? r2 : 0)) + 1;
          ta = (e0 == t2v) ? br.x : ((e0 + e1 == t2v) ? br.y : br.z);
          found = true;
        } else {
          bsc += 2;
        }
        kka = ca; kkb = cb;
      }
      if (found) {
        to_add = ta; hit = true; bsf = bsc;
      } else {
        uint32_t k3a, k3b, rhi, rlo;
        tf2x32(kia, kib, 0u, 3u, k3a, k3b);
        randbits(k3a, k3b, rhi, rlo);
        to_add = (int)r_generic(rhi, rlo, (uint32_t)N);
      }
    }

    int i_new, up;
    if (hit) { i_new = i - bsf; bs = bsf; up = i - 1; }
    else     { i_new = i;       bs = 1;   up = i; }
    seqr = (lane >= i_new && lane <= up) ? to_add : seqr;

    const int slot = idx + 1;
    if (slot < CH)            hist  = (lane == slot)      ? to_add : hist;
    else if (slot < 2 * CH)   hist2 = (lane == slot - CH) ? to_add : hist2;

    i = i_new + 1;

    if (sel >= 0) {
      row.x = (sel == 0) ? t0.x : ((sel == 1) ? t1.x : t2.x);
      row.y = (sel == 0) ? t0.y : ((sel == 1) ? t1.y : t2.y);
      row.z = (sel == 0) ? t0.z : ((sel == 1) ? t1.z : t2.z);
    } else {
      row = *reinterpret_cast<const int3*>(nb + 3 * (size_t)to_add);
    }
    t0 = *reinterpret_cast<const int3*>(nb + 3 * (size_t)row.x);
    t1 = *reinterpret_cast<const int3*>(nb + 3 * (size_t)row.y);
    t2 = *reinterpret_cast<const int3*>(nb + 3 * (size_t)row.z);
  }

  const float cx = xb[3 * (size_t)f0 + 0];
  const float cy = xb[3 * (size_t)f0 + 1];
  const float cz = xb[3 * (size_t)f0 + 2];
  if (lane < Lp1) {
    const int node = seqr;
    float3 v;
    v.x = xb[3 * (size_t)node + 0] - cx;
    v.y = xb[3 * (size_t)node + 1] - cy;
    v.z = xb[3 * (size_t)node + 2] - cz;
    *reinterpret_cast<float3*>(out + ((size_t)w * Lp1 + lane) * 3) = v;
  }
}

}  // namespace

extern "C" void kernel_launch(void* const* d_in, const int* in_sizes, int n_in,
                              void* d_out, int out_size, void* d_ws, size_t ws_size,
                              hipStream_t stream) {
  const float* xyz     = (const float*)d_in[0];
  const int*   nbrs    = (const int*)d_in[1];
  const int*   centers = (const int*)d_in[2];
  const int*   n_faces = (const int*)d_in[3];
  const int*   seq_len = (const int*)d_in[4];
  float* out = (float*)d_out;

  const int s0 = in_sizes[0];                  // B*N*3
  const int num_walks = in_sizes[2];           // B*G = 4096
  const int Lp1 = out_size / (3 * num_walks);  // 64

  const size_t keys_bytes  = (size_t)num_walks * CH * sizeof(uint2);
  const size_t codes_bytes = (size_t)num_walks * CH * sizeof(uint32_t);

  if (ws_size >= keys_bytes + codes_bytes) {
    uint2*    keys_g  = (uint2*)d_ws;
    uint32_t* codes_g = (uint32_t*)((char*)d_ws + keys_bytes);

    const int blocks1 = (num_walks + K1_WPB - 1) / K1_WPB;   // 256
    keys_kernel<<<blocks1, K1_WPB * 64, 0, stream>>>(keys_g, codes_g, num_walks);

    const int blocks2 = (num_walks + K2_WPB - 1) / K2_WPB;   // 1024
    walk_kernel<<<blocks2, K2_WPB * 64, 0, stream>>>(
        xyz, nbrs, centers, n_faces, seq_len, out, keys_g, codes_g,
        s0, num_walks, Lp1);
  } else {
    const int blocks = (num_walks + K1_WPB - 1) / K1_WPB;    // 256
    fused_kernel<<<blocks, K1_WPB * 64, 0, stream>>>(
        xyz, nbrs, centers, n_faces, seq_len, out, s0, num_walks, Lp1);
  }
}

// Round 6
// 104.578 us; speedup vs baseline: 1.0795x; 1.0795x over previous
//
#include <hip/hip_runtime.h>
#include <stdint.h>
#include <stddef.h>

// MambaMesh random-walk + gather-recenter.  R6: LDS-resident neighbor table.
// PRNG (bit-exact vs JAX partitionable Threefry, verified R1-R5, absmax 0.0):
//   split(key,n)[j]        = threefry2x32(key; 0, j)   (both output words)
//   random_bits(key,32,()) = xor-fold of threefry2x32(key; 0, 0)
// R5 attribution: walk loop alone = 41 us (~1550 cyc/step) — a cold HBM
// pointer-chase; FETCH 7.5 MB = nb-table x 8 XCDs refetched every replay
// (harness input-restore invalidates caches). Caching tricks can't stick.
// R6: pack nb into LDS as 3x uint16[N] (120 KB < 160 KB LDS) — the chase
// becomes deterministic ~120-cyc ds_read latency, eviction-immune.
//   block = 1024 thr = 16 waves = 16 walks, 1 block/CU, uniform batch/block.
//   stage (waves 1-15, ~2 us) || chains (wave 0, ~6-9 us serial floor);
//   walk: candidate-row LDS prefetch overlaps decide ALU (~170 cyc/step).

namespace {

__device__ __forceinline__ uint32_t rotl32(uint32_t x, int r) {
  return (x << r) | (x >> (32 - r));
}

// Threefry-2x32, 20 rounds — exactly JAX's threefry2x32_p.
__device__ __forceinline__ void tf2x32(uint32_t ka, uint32_t kb,
                                       uint32_t x0, uint32_t x1,
                                       uint32_t& o0, uint32_t& o1) {
  const uint32_t kc = ka ^ kb ^ 0x1BD11BDAu;
  x0 += ka; x1 += kb;
#define TF_R4(r0, r1, r2, r3)                          \
  x0 += x1; x1 = rotl32(x1, r0); x1 ^= x0;             \
  x0 += x1; x1 = rotl32(x1, r1); x1 ^= x0;             \
  x0 += x1; x1 = rotl32(x1, r2); x1 ^= x0;             \
  x0 += x1; x1 = rotl32(x1, r3); x1 ^= x0;
  TF_R4(13, 15, 26, 6)  x0 += kb; x1 += kc + 1u;
  TF_R4(17, 29, 16, 24) x0 += kc; x1 += ka + 2u;
  TF_R4(13, 15, 26, 6)  x0 += ka; x1 += kb + 3u;
  TF_R4(17, 29, 16, 24) x0 += kb; x1 += kc + 4u;
  TF_R4(13, 15, 26, 6)  x0 += kc; x1 += ka + 5u;
#undef TF_R4
  o0 = x0; o1 = x1;
}

// (hi, lo) bits of jax.random.randint(key, (), 0, span): span-independent.
__device__ __forceinline__ void randbits(uint32_t ka, uint32_t kb,
                                         uint32_t& hi, uint32_t& lo) {
  uint32_t s0a, s0b, s1a, s1b, h0, h1;
  tf2x32(ka, kb, 0u, 0u, s0a, s0b);   // split(key)[0]
  tf2x32(ka, kb, 0u, 1u, s1a, s1b);   // split(key)[1]
  tf2x32(s0a, s0b, 0u, 0u, h0, h1);
  hi = h0 ^ h1;
  tf2x32(s1a, s1b, 0u, 0u, h0, h1);
  lo = h0 ^ h1;
}

__device__ __forceinline__ uint32_t r_generic(uint32_t hi, uint32_t lo,
                                              uint32_t span) {
  uint32_t mult = 65536u % span;
  mult = (mult * mult) % span;
  return ((hi % span) * mult + (lo % span)) % span;
}

// pick code: r3 (span=3 result) in bits 0..1, r2 (span=2 result) in bit 2.
__device__ __forceinline__ uint32_t pick_code(uint32_t hi, uint32_t lo) {
  return ((hi % 3u + lo % 3u) % 3u) | ((lo & 1u) << 2);
}

constexpr int WPB = 16;      // walks per block (one per wave; 1024 threads)
constexpr int CH = 64;       // cached chain length (covers seq_len 63)
constexpr int KSTRIDE = 65;  // keysL stride in uint2 (65 breaks bank alias)

// ---------------- Main kernel: LDS-table walk -----------------------------
__global__ __launch_bounds__(1024) void walk_lds_kernel(
    const float* __restrict__ xyz, const int* __restrict__ nbrs,
    const int* __restrict__ centers, const int* __restrict__ n_faces_p,
    const int* __restrict__ seq_len_p, float* __restrict__ out,
    int s0, int num_walks, int Lp1) {
  extern __shared__ char smem[];

  const int tid = threadIdx.x;
  const int wv = tid >> 6, lane = tid & 63;
  const int w0 = blockIdx.x * WPB;
  if (w0 >= num_walks) return;           // whole-block uniform
  const int w = w0 + wv;
  const bool active = (w < num_walks);

  const int N = *n_faces_p;    // 20000
  const int L = *seq_len_p;    // 63
  const int B = s0 / (3 * N);
  const int G = num_walks / B;
  const int b = w0 / G;        // uniform per block (host guarantees G%WPB==0)
  const int* __restrict__ nb   = nbrs + (size_t)b * N * 3;
  const float* __restrict__ xb = xyz + (size_t)b * N * 3;

  const int Npad = (N + 3) & ~3;
  uint16_t* nb0L = (uint16_t*)smem;
  uint16_t* nb1L = nb0L + Npad;
  uint16_t* nb2L = nb1L + Npad;
  uint2* keysL = (uint2*)(smem + (((size_t)6 * Npad + 7) & ~(size_t)7));

  // Early global reads (fly during stage/chain phase).
  const int f0 = active ? centers[w] : 0;

  // ---- Stage (waves 1..15) || carry-key chains (wave 0) ------------------
  if (wv == 0) {
    if (lane < WPB && (w0 + lane) < num_walks) {
      uint32_t ka, kb;
      tf2x32(0u, 42u, 0u, (uint32_t)(w0 + lane), ka, kb);  // k_0
      keysL[lane * KSTRIDE + 0] = make_uint2(ka, kb);
#pragma clang loop unroll(disable)
      for (int c = 1; c < CH; ++c) {
        tf2x32(ka, kb, 0u, 0u, ka, kb);
        keysL[lane * KSTRIDE + c] = make_uint2(ka, kb);
      }
    }
  } else {
    for (int r = tid - 64; r < N; r += 960) {
      const int3 v = *reinterpret_cast<const int3*>(nb + 3 * (size_t)r);
      nb0L[r] = (uint16_t)v.x;
      nb1L[r] = (uint16_t)v.y;
      nb2L[r] = (uint16_t)v.z;
    }
  }
  __syncthreads();
  if (!active) return;

  // ---- Per-step randint tree: lane c = step c (wave-local) ---------------
  const uint2 mykey = keysL[wv * KSTRIDE + lane];
  uint32_t mycode;
  {
    uint32_t k1a, k1b, hi, lo;
    tf2x32(mykey.x, mykey.y, 0u, 1u, k1a, k1b);  // k1 = split(k,4)[1]
    randbits(k1a, k1b, hi, lo);
    mycode = pick_code(hi, lo);
  }

  // ---- Walk: pure LDS chase ---------------------------------------------
  // visited set: lane j holds the j-th visited node (slot 0 = f0).
  int hist  = (lane == 0) ? f0 : -1;
  int hist2 = -1;              // slots 64..127 (backtrack overflow; ~never)
  int seqr  = (lane == 0) ? f0 : -1;  // lane t = seq[t]

  uint32_t extka = 0, extkb = 0;
  int extc = -1;  // lazy chain extension beyond CH (only after backtracks)

  auto get_key = [&](int idx, uint32_t& ra, uint32_t& rb) {
    if (idx < CH) {
      const uint2 q = keysL[wv * KSTRIDE + idx]; ra = q.x; rb = q.y;
    } else {
      if (extc < 0) {
        const uint2 q = keysL[wv * KSTRIDE + (CH - 1)];
        extka = q.x; extkb = q.y; extc = CH - 1;
      }
      while (extc < idx) { tf2x32(extka, extkb, 0u, 0u, extka, extkb); ++extc; }
      ra = extka; rb = extkb;
    }
  };

  int n0 = nb0L[f0], n1 = nb1L[f0], n2 = nb2L[f0];  // row of cur
  uint32_t code_next = (uint32_t)__shfl((int)mycode, 0);
  int i = 1, bs = 1, c = 0;

  while (i <= L) {
    const int idx = c; ++c;
    const bool deep = (idx >= CH);  // hist2 in use
    const uint32_t codeP = code_next;
    code_next = (uint32_t)__shfl((int)mycode, (c < CH) ? c : 0);  // prefetch

    // Prefetch all 3 candidate rows from LDS; decide overlaps the flight.
    const int a0 = nb0L[n0], a1 = nb1L[n0], a2 = nb2L[n0];
    const int b0 = nb0L[n1], b1 = nb1L[n1], b2 = nb2L[n1];
    const int c0 = nb0L[n2], c1 = nb1L[n2], c2 = nb2L[n2];

    int v0 = __any(hist == n0), v1 = __any(hist == n1), v2 = __any(hist == n2);
    if (deep) {
      v0 |= __any(hist2 == n0); v1 |= __any(hist2 == n1); v2 |= __any(hist2 == n2);
    }
    const int u0 = 1 - v0, u1 = 1 - v1, u2 = 1 - v2;
    const int cnt = u0 + u1 + u2;

    int to_add;
    int sel = -1;        // >=0: common path, next row from candidates
    bool hit = false;
    int bsf = bs;
    if (cnt > 0) {
      uint32_t code;
      if (!deep) {
        code = codeP;
      } else {  // rare: live tree beyond cached steps
        uint32_t ia, ib, k1a, k1b, hi, lo;
        get_key(idx, ia, ib);
        tf2x32(ia, ib, 0u, 1u, k1a, k1b);
        randbits(k1a, k1b, hi, lo);
        code = pick_code(hi, lo);
      }
      const int r3 = (int)(code & 3u), r2 = (int)((code >> 2) & 1u);
      const int target = (cnt == 3 ? r3 : (cnt == 2 ? r2 : 0)) + 1;
      sel = (u0 == target) ? 0 : ((u0 + u1 == target) ? 1 : 2);
      to_add = (sel == 0) ? n0 : ((sel == 1) ? n1 : n2);
    } else {
      // ---- rare backtrack path (live hashing, bit-exact) ----
      uint32_t kia, kib;
      get_key(idx, kia, kib);
      uint32_t kka, kkb;
      tf2x32(kia, kib, 0u, 2u, kka, kkb);  // k2
      bool found = false;
      int ta = 0, bsc = bs;
      while (!found && i > bsc) {
        uint32_t ca, cb, kpa, kpb;
        tf2x32(kka, kkb, 0u, 0u, ca, cb);    // kk = split[0]
        tf2x32(kka, kkb, 0u, 1u, kpa, kpb);  // kp = split[1]
        const int back = __shfl(seqr, i - bsc - 1);
        const int m0 = nb0L[back], m1 = nb1L[back], m2 = nb2L[back];
        int w0m = __any(hist == m0), w1m = __any(hist == m1), w2m = __any(hist == m2);
        if (deep) {
          w0m |= __any(hist2 == m0); w1m |= __any(hist2 == m1); w2m |= __any(hist2 == m2);
        }
        const int e0 = 1 - w0m, e1 = 1 - w1m, e2 = 1 - w2m;
        const int bc = e0 + e1 + e2;
        if (bc > 0) {
          uint32_t bhi, blo;
          randbits(kpa, kpb, bhi, blo);
          const uint32_t bcode = pick_code(bhi, blo);
          const int r3 = (int)(bcode & 3u), r2 = (int)((bcode >> 2) & 1u);
          const int t2v = (bc == 3 ? r3 : (bc == 2 ? r2 : 0)) + 1;
          ta = (e0 == t2v) ? m0 : ((e0 + e1 == t2v) ? m1 : m2);
          found = true;
        } else {
          bsc += 2;
        }
        kka = ca; kkb = cb;
      }
      if (found) {
        to_add = ta; hit = true; bsf = bsc;
      } else {
        uint32_t k3a, k3b, rhi, rlo;
        tf2x32(kia, kib, 0u, 3u, k3a, k3b);  // k3
        randbits(k3a, k3b, rhi, rlo);
        to_add = (int)r_generic(rhi, rlo, (uint32_t)N);
      }
    }

    int i_new, up;
    if (hit) { i_new = i - bsf; bs = bsf; up = i - 1; }   // splat [i_new, i)
    else     { i_new = i;       bs = 1;   up = i; }
    seqr = (lane >= i_new && lane <= up) ? to_add : seqr;

    const int slot = idx + 1;
    if (slot < CH)            hist  = (lane == slot)      ? to_add : hist;
    else if (slot < 2 * CH)   hist2 = (lane == slot - CH) ? to_add : hist2;
    // slot >= 128: needs ~32 backtracks in one walk — P < 1e-100 here.

    i = i_new + 1;

    // Next row: common path = candidate select; rare = direct LDS read.
    if (sel == 0)      { n0 = a0; n1 = a1; n2 = a2; }
    else if (sel == 1) { n0 = b0; n1 = b1; n2 = b2; }
    else if (sel == 2) { n0 = c0; n1 = c1; n2 = c2; }
    else { n0 = nb0L[to_add]; n1 = nb1L[to_add]; n2 = nb2L[to_add]; }
  }

  // ---- Epilogue: lane t holds seq[t] ------------------------------------
  const float cx = xb[3 * (size_t)f0 + 0];
  const float cy = xb[3 * (size_t)f0 + 1];
  const float cz = xb[3 * (size_t)f0 + 2];
  if (lane < Lp1) {
    const int node = seqr;
    float3 v;
    v.x = xb[3 * (size_t)node + 0] - cx;
    v.y = xb[3 * (size_t)node + 1] - cy;
    v.z = xb[3 * (size_t)node + 2] - cz;
    *reinterpret_cast<float3*>(out + ((size_t)w * Lp1 + lane) * 3) = v;
  }
}

// ---------------- Fallback: fused global-chase kernel (R5, verified) ------
__global__ __launch_bounds__(1024) void fused_kernel(
    const float* __restrict__ xyz, const int* __restrict__ nbrs,
    const int* __restrict__ centers, const int* __restrict__ n_faces_p,
    const int* __restrict__ seq_len_p, float* __restrict__ out,
    int s0, int num_walks, int Lp1) {
  __shared__ uint2 keys[WPB][CH + 1];
  __shared__ uint32_t pre[WPB][CH];

  const int tid = threadIdx.x;
  const int wv = tid >> 6, lane = tid & 63;
  const int w0 = blockIdx.x * WPB;
  const int w = w0 + wv;
  const bool active = (w < num_walks);

  const int N = *n_faces_p;
  const int L = *seq_len_p;
  const int B = s0 / (3 * N);
  const int G = num_walks / B;
  const int b = (active ? w : w0) / G;
  const int* __restrict__ nb   = nbrs + (size_t)b * N * 3;
  const float* __restrict__ xb = xyz + (size_t)b * N * 3;

  int f0 = 0;
  int3 row = make_int3(0, 0, 0);
  if (active) {
    f0 = centers[w];
    row = *reinterpret_cast<const int3*>(nb + 3 * (size_t)f0);
  }

  if (wv == 0 && lane < WPB && (w0 + lane) < num_walks) {
    uint32_t ka, kb;
    tf2x32(0u, 42u, 0u, (uint32_t)(w0 + lane), ka, kb);
    keys[lane][0] = make_uint2(ka, kb);
#pragma clang loop unroll(disable)
    for (int c = 1; c < CH; ++c) {
      tf2x32(ka, kb, 0u, 0u, ka, kb);
      keys[lane][c] = make_uint2(ka, kb);
    }
  }
  __syncthreads();
  if (!active) return;

  {
    const uint2 kc = keys[wv][lane];
    uint32_t k1a, k1b, hi, lo;
    tf2x32(kc.x, kc.y, 0u, 1u, k1a, k1b);
    randbits(k1a, k1b, hi, lo);
    pre[wv][lane] = pick_code(hi, lo);
  }

  int hist  = (lane == 0) ? f0 : -1;
  int hist2 = -1;
  int seqr  = (lane == 0) ? f0 : -1;

  uint32_t extka = 0, extkb = 0;
  int extc = -1;

  auto get_key = [&](int idx, uint32_t& ra, uint32_t& rb) {
    if (idx < CH) {
      const uint2 q = keys[wv][idx]; ra = q.x; rb = q.y;
    } else {
      if (extc < 0) { const uint2 q = keys[wv][CH - 1]; extka = q.x; extkb = q.y; extc = CH - 1; }
      while (extc < idx) { tf2x32(extka, extkb, 0u, 0u, extka, extkb); ++extc; }
      ra = extka; rb = extkb;
    }
  };

  uint32_t code_next = pre[wv][0];
  int i = 1, bs = 1, c = 0;

  while (i <= L) {
    const int idx = c; ++c;
    const bool deep = (idx >= CH);
    const uint32_t codeP = code_next;
    code_next = pre[wv][(c < CH) ? c : 0];

    const int n0 = row.x, n1 = row.y, n2 = row.z;
    int v0 = __any(hist == n0), v1 = __any(hist == n1), v2 = __any(hist == n2);
    if (deep) {
      v0 |= __any(hist2 == n0); v1 |= __any(hist2 == n1); v2 |= __any(hist2 == n2);
    }
    const int u0 = 1 - v0, u1 = 1 - v1, u2 = 1 - v2;
    const int cnt = u0 + u1 + u2;

    int to_add;
    bool hit = false;
    int bsf = bs;
    if (cnt > 0) {
      uint32_t code;
      if (!deep) {
        code = codeP;
      } else {
        uint32_t ia, ib, k1a, k1b, hi, lo;
        get_key(idx, ia, ib);
        tf2x32(ia, ib, 0u, 1u, k1a, k1b);
        randbits(k1a, k1b, hi, lo);
        code = pick_code(hi, lo);
      }
      const int r3 = (int)(code & 3u), r2 = (int)((code >> 2) & 1u);
      const int target = (cnt == 3 ? r3 : (cnt == 2 ? r2 : 0)) + 1;
      to_add = (u0 == target) ? n0 : ((u0 + u1 == target) ? n1 : n2);
    } else {
      uint32_t kia, kib;
      get_key(idx, kia, kib);
      uint32_t kka, kkb;
      tf2x32(kia, kib, 0u, 2u, kka, kkb);
      bool found = false;
      int ta = 0, bsc = bs;
      while (!found && i > bsc) {
        uint32_t ca, cb, kpa, kpb;
        tf2x32(kka, kkb, 0u, 0u, ca, cb);
        tf2x32(kka, kkb, 0u, 1u, kpa, kpb);
        const int back = __shfl(seqr, i - bsc - 1);
        const int3 br = *reinterpret_cast<const int3*>(nb + 3 * (size_t)back);
        int w0m = __any(hist == br.x), w1m = __any(hist == br.y), w2m = __any(hist == br.z);
        if (deep) {
          w0m |= __any(hist2 == br.x); w1m |= __any(hist2 == br.y); w2m |= __any(hist2 == br.z);
        }
        const int e0 = 1 - w0m, e1 = 1 - w1m, e2 = 1 - w2m;
        const int bc = e0 + e1 + e2;
        if (bc > 0) {
          uint32_t bhi, blo;
          randbits(kpa, kpb, bhi, blo);
          const uint32_t bcode = pick_code(bhi, blo);
          const int r3 = (int)(bcode & 3u), r2 = (int)((bcode >> 2) & 1u);
          const int t2v = (bc == 3 ? r3 : (bc == 2 ? r2 : 0)) + 1;
          ta = (e0 == t2v) ? br.x : ((e0 + e1 == t2v) ? br.y : br.z);
          found = true;
        } else {
          bsc += 2;
        }
        kka = ca; kkb = cb;
      }
      if (found) {
        to_add = ta; hit = true; bsf = bsc;
      } else {
        uint32_t k3a, k3b, rhi, rlo;
        tf2x32(kia, kib, 0u, 3u, k3a, k3b);
        randbits(k3a, k3b, rhi, rlo);
        to_add = (int)r_generic(rhi, rlo, (uint32_t)N);
      }
    }

    int i_new, up;
    if (hit) { i_new = i - bsf; bs = bsf; up = i - 1; }
    else     { i_new = i;       bs = 1;   up = i; }
    seqr = (lane >= i_new && lane <= up) ? to_add : seqr;

    const int slot = idx + 1;
    if (slot < CH)            hist  = (lane == slot)      ? to_add : hist;
    else if (slot < 2 * CH)   hist2 = (lane == slot - CH) ? to_add : hist2;

    i = i_new + 1;
    row = *reinterpret_cast<const int3*>(nb + 3 * (size_t)to_add);
  }

  const float cx = xb[3 * (size_t)f0 + 0];
  const float cy = xb[3 * (size_t)f0 + 1];
  const float cz = xb[3 * (size_t)f0 + 2];
  if (lane < Lp1) {
    const int node = seqr;
    float3 v;
    v.x = xb[3 * (size_t)node + 0] - cx;
    v.y = xb[3 * (size_t)node + 1] - cy;
    v.z = xb[3 * (size_t)node + 2] - cz;
    *reinterpret_cast<float3*>(out + ((size_t)w * Lp1 + lane) * 3) = v;
  }
}

}  // namespace

extern "C" void kernel_launch(void* const* d_in, const int* in_sizes, int n_in,
                              void* d_out, int out_size, void* d_ws, size_t ws_size,
                              hipStream_t stream) {
  const float* xyz     = (const float*)d_in[0];
  const int*   nbrs    = (const int*)d_in[1];
  const int*   centers = (const int*)d_in[2];
  const int*   n_faces = (const int*)d_in[3];
  const int*   seq_len = (const int*)d_in[4];
  float* out = (float*)d_out;

  const int s0 = in_sizes[0];                  // B*N*3
  const int num_walks = in_sizes[2];           // B*G = 4096
  const int Lp1 = out_size / (3 * num_walks);  // 64

  // Shapes are fixed per-problem; N known on host from in_sizes.
  const int s1 = in_sizes[1];                  // B*N*3 (ints)
  // N from s0/s1 relationship: both are B*N*3; need N itself — derive from
  // the known constraint centers: num_walks = B*G. We can't read device
  // scalars here, so recover N via s0: B*N*3 = s0 and B = s0 / (3*N).
  // Instead use: nbrs size == xyz size == B*N*3. The harness gives n_faces
  // only on device; but B is the only unknown pair. For the fixed problem
  // B=4, N=20000. Derive robustly: try each B in {1,2,4,8,16} that divides
  // both s0/3 and num_walks, pick the one giving N <= 65535 and G%WPB==0.
  int bestN = -1;
  for (int Bc = 1; Bc <= 64; Bc <<= 1) {
    if (num_walks % Bc) continue;
    if ((s0 % (3 * Bc))) continue;
    const int Nc = s0 / (3 * Bc);
    const int Gc = num_walks / Bc;
    if (Nc <= 65535 && Nc >= Gc && (Gc % WPB) == 0) { bestN = Nc; break; }
  }
  (void)s1;

  bool use_lds = false;
  size_t lds_bytes = 0;
  if (bestN > 0) {
    const int Npad = (bestN + 3) & ~3;
    lds_bytes = (((size_t)6 * Npad + 7) & ~(size_t)7) +
                (size_t)WPB * KSTRIDE * sizeof(uint2);
    if (lds_bytes <= 160 * 1024 - 1024) {
      use_lds = true;
      // Allow >64KB dynamic LDS (no-op if unsupported; check result).
      hipError_t e = hipFuncSetAttribute(
          (const void*)walk_lds_kernel,
          hipFuncAttributeMaxDynamicSharedMemorySize, (int)lds_bytes);
      if (e != hipSuccess) {
        // Some ROCm builds cap dynamic LDS; only trust <=64KB then.
        if (lds_bytes > 64 * 1024) use_lds = false;
      }
    }
  }

  const int blocks = (num_walks + WPB - 1) / WPB;  // 256
  if (use_lds) {
    walk_lds_kernel<<<blocks, WPB * 64, lds_bytes, stream>>>(
        xyz, nbrs, centers, n_faces, seq_len, out, s0, num_walks, Lp1);
  } else {
    fused_kernel<<<blocks, WPB * 64, 0, stream>>>(
        xyz, nbrs, centers, n_faces, seq_len, out, s0, num_walks, Lp1);
  }
}